// Round 9
// baseline (454.725 us; speedup 1.0000x reference)
//
#include <hip/hip_runtime.h>

#define NB 8
#define NN 10000
#define NE 160000
#define NNODES (NB*NN)          // 80000
#define NEDGE (NB*NE)           // 1280000
#define FIN 5
#define HID 128
#define EMB 256
#define ALAST 10
#define PROJ_IN (HID*5 + ALAST + 1)  // 651
#define NBLK ((NNODES+255)/256)      // 313
#define GB 32                        // blocks per graph for CSR build
#define EPB (NE/GB)                  // 5000 edges per block

// ---- CSR build, no global atomics ----
__global__ __launch_bounds__(256) void k_histL(const int* __restrict__ edges,
                                               int* __restrict__ hist,
                                               int* __restrict__ rankL) {
    int g = blockIdx.x & 7;                 // XCD pin
    int b = blockIdx.x >> 3;                // 0..GB-1
    __shared__ __align__(16) int c[NN];
    int4* c4 = (int4*)c;
    for (int i = threadIdx.x; i < NN/4; i += 256) c4[i] = make_int4(0,0,0,0);
    __syncthreads();
    const int* dstp = edges + (size_t)g*2*NE + NE + b*EPB;
    int* rl = rankL + (size_t)g*NE + b*EPB;
    const int4* d4p = (const int4*)dstp;
    for (int i = threadIdx.x; i < EPB/4; i += 256) {
        int4 d4 = d4p[i];
        int e0 = 4*i;
        rl[e0+0] = atomicAdd(&c[d4.x], 1);
        rl[e0+1] = atomicAdd(&c[d4.y], 1);
        rl[e0+2] = atomicAdd(&c[d4.z], 1);
        rl[e0+3] = atomicAdd(&c[d4.w], 1);
    }
    __syncthreads();
    int4* hp = (int4*)(hist + (size_t)(g*GB + b)*NN);
    for (int i = threadIdx.x; i < NN/4; i += 256) hp[i] = c4[i];
}

// per-dst prefix across the GB block-hists; emit cnt, leave block offsets in hist
__global__ void k_scanB(int* __restrict__ hist, int* __restrict__ cnt) {
    int n = blockIdx.x*256 + threadIdx.x;
    if (n >= NNODES) return;
    int g = n / NN, dl = n - g*NN;
    int* hbase = hist + (size_t)g*GB*NN + dl;
    int run = 0;
    #pragma unroll
    for (int b = 0; b < GB; ++b) {
        int v = hbase[(size_t)b*NN];
        hbase[(size_t)b*NN] = run;          // exclusive within-dst offset
        run += v;
    }
    cnt[n] = run;
}

__global__ void k_scan1(const int* __restrict__ cnt, int* __restrict__ rowStart,
                        int* __restrict__ bsum) {
    __shared__ int sh[256];
    int tid = threadIdx.x;
    int i = blockIdx.x*256 + tid;
    int v = (i < NNODES) ? cnt[i] : 0;
    sh[tid] = v;
    __syncthreads();
    for (int off = 1; off < 256; off <<= 1) {
        int t = (tid >= off) ? sh[tid - off] : 0;
        __syncthreads();
        sh[tid] += t;
        __syncthreads();
    }
    if (i < NNODES) rowStart[i] = sh[tid] - v;          // exclusive
    if (tid == 255) bsum[blockIdx.x] = sh[255];
}

__global__ void k_scan2(int* bsum) {
    __shared__ int sh[512];
    int tid = threadIdx.x;
    int v = (tid < NBLK) ? bsum[tid] : 0;
    sh[tid] = v;
    __syncthreads();
    for (int off = 1; off < 512; off <<= 1) {
        int t = (tid >= off) ? sh[tid - off] : 0;
        __syncthreads();
        sh[tid] += t;
        __syncthreads();
    }
    if (tid < NBLK) bsum[tid] = sh[tid] - v;            // exclusive
}

// add block offsets; compute dinv; prescale 5-dim features into SoA xs5
__global__ void k_scan3(int* __restrict__ rowStart, const int* __restrict__ bsum,
                        const int* __restrict__ cnt, float* __restrict__ dinv,
                        const float* __restrict__ x, float* __restrict__ xs5) {
    int i = blockIdx.x*256 + threadIdx.x;
    if (i < NNODES) {
        rowStart[i] = rowStart[i] + bsum[blockIdx.x];
        float dv = rsqrtf(1.0f + (float)cnt[i]);        // +1 = self loop
        dinv[i] = dv;
        #pragma unroll
        for (int f = 0; f < FIN; ++f)
            xs5[f*NNODES + i] = x[(size_t)i*FIN + f] * dv;
    }
    if (i == 0) rowStart[NNODES] = NEDGE;
}

// p = rowStart[dst] + blockOffset[b][dst] + rank_local[e]; plain stores only.
__global__ __launch_bounds__(256) void k_fillL(const int* __restrict__ edges,
                                               const int* __restrict__ rowStart,
                                               const int* __restrict__ hist,
                                               const int* __restrict__ rankL,
                                               int* __restrict__ csrSrc) {
    int g = blockIdx.x & 7;
    int b = blockIdx.x >> 3;
    const int* base = edges + (size_t)g*2*NE;
    const int4* s4p = (const int4*)(base + b*EPB);
    const int4* d4p = (const int4*)(base + NE + b*EPB);
    const int4* r4p = (const int4*)(rankL + (size_t)g*NE + b*EPB);
    const int* rs = rowStart + g*NN;
    const int* ho = hist + (size_t)(g*GB + b)*NN;
    int gofs = g*NN;
    for (int i = threadIdx.x; i < EPB/4; i += 256) {
        int4 s4 = s4p[i];
        int4 d4 = d4p[i];
        int4 r4 = r4p[i];
        csrSrc[rs[d4.x] + ho[d4.x] + r4.x] = s4.x + gofs;
        csrSrc[rs[d4.y] + ho[d4.y] + r4.y] = s4.y + gofs;
        csrSrc[rs[d4.z] + ho[d4.z] + r4.z] = s4.z + gofs;
        csrSrc[rs[d4.w] + ho[d4.w] + r4.w] = s4.w + gofs;
    }
}

// layer-1 aggregation on the 5 raw features (agg commutes with dense transform).
__global__ __launch_bounds__(256) void k_agg5(
        const int* __restrict__ rowStart, const int* __restrict__ csrSrc,
        const float* __restrict__ xs5, const float* __restrict__ dinv,
        float* __restrict__ ax) {
    int g = blockIdx.x;
    int graph = g & 7;
    int nl = (g >> 3)*256 + threadIdx.x;
    if (nl >= NN) return;
    int n = graph*NN + nl;
    float a0 = xs5[0*NNODES + n], a1 = xs5[1*NNODES + n], a2 = xs5[2*NNODES + n],
          a3 = xs5[3*NNODES + n], a4 = xs5[4*NNODES + n];
    int beg = rowStart[n], end = rowStart[n+1];
    for (int e = beg; e < end; ++e) {
        int s = csrSrc[e];
        a0 += xs5[0*NNODES + s];
        a1 += xs5[1*NNODES + s];
        a2 += xs5[2*NNODES + s];
        a3 += xs5[3*NNODES + s];
        a4 += xs5[4*NNODES + s];
    }
    float dv = dinv[n];
    ax[(size_t)n*FIN + 0] = a0*dv;
    ax[(size_t)n*FIN + 1] = a1*dv;
    ax[(size_t)n*FIN + 2] = a2*dv;
    ax[(size_t)n*FIN + 3] = a3*dv;
    ax[(size_t)n*FIN + 4] = a4*dv;
}

// Fused layer-1 dense + layer-2 dense, 64x128 tile (grid 1250 for occupancy):
// H1 = relu(ax @ W1^T + b1) on the fly; hs = (H1 @ W2^T) * dinv.
// Per thread: 4 rows x 8 cols.
#define KC 32
__global__ __launch_bounds__(256) void k_h12(
        const float* __restrict__ ax, const float* __restrict__ W1,
        const float* __restrict__ b1, const float* __restrict__ W2,
        const float* __restrict__ dinv, float* __restrict__ hs) {
    __shared__ float axs[FIN][64];
    __shared__ float w1s[FIN][128];
    __shared__ float b1s[128];
    __shared__ float xs[KC*64];
    __shared__ float wt[KC*128];
    int tid = threadIdx.x;
    int m0g = blockIdx.x * 64;
    if (tid < 128) {
        b1s[tid] = b1[tid];
        #pragma unroll
        for (int f = 0; f < FIN; ++f) w1s[f][tid] = W1[tid*FIN + f];
    } else if (tid < 192) {
        int r2 = tid - 128;
        #pragma unroll
        for (int f = 0; f < FIN; ++f) axs[f][r2] = ax[(size_t)(m0g + r2)*FIN + f];
    }
    int tx = tid & 15, ty = tid >> 4;
    int m0 = ty*4;                      // 16 groups x 4 rows = 64
    int j0 = tx*4;
    int rw  = tid >> 1;                 // W2 staging row 0..127
    int kqw = (tid & 1) * 16;
    int rx  = tid & 63;                 // H1 staging row 0..63 (wave-contiguous)
    int kqx = (tid >> 6) * 8;           // 4 k-groups of 8
    float a[4][8];
    #pragma unroll
    for (int i = 0; i < 4; ++i)
        #pragma unroll
        for (int j = 0; j < 8; ++j) a[i][j] = 0.f;
    __syncthreads();
    float axr[FIN];
    #pragma unroll
    for (int f = 0; f < FIN; ++f) axr[f] = axs[f][rx];

    for (int kh = 0; kh < 128; kh += KC) {
        float4 wv[4];
        #pragma unroll
        for (int c = 0; c < 4; ++c)
            wv[c] = *(const float4*)&W2[(size_t)rw*128 + kh + kqw + 4*c];
        float hv[8];
        #pragma unroll
        for (int kk = 0; kk < 8; ++kk) {
            int k1 = kh + kqx + kk;
            float sv = b1s[k1];
            #pragma unroll
            for (int f = 0; f < FIN; ++f) sv += axr[f]*w1s[f][k1];
            hv[kk] = fmaxf(sv, 0.0f);
        }
        __syncthreads();               // protect prev iter's reads
        #pragma unroll
        for (int kk = 0; kk < 8; ++kk) xs[(kqx+kk)*64 + rx] = hv[kk];
        #pragma unroll
        for (int c = 0; c < 4; ++c) {
            wt[(kqw+4*c+0)*128 + rw] = wv[c].x;
            wt[(kqw+4*c+1)*128 + rw] = wv[c].y;
            wt[(kqw+4*c+2)*128 + rw] = wv[c].z;
            wt[(kqw+4*c+3)*128 + rw] = wv[c].w;
        }
        __syncthreads();
        for (int k = 0; k < KC; ++k) {
            float4 xa = *(const float4*)&xs[k*64 + m0];
            float4 wa = *(const float4*)&wt[k*128 + j0];
            float4 wb = *(const float4*)&wt[k*128 + j0 + 64];
            float xr[4] = {xa.x,xa.y,xa.z,xa.w};
            float wr[8] = {wa.x,wa.y,wa.z,wa.w,wb.x,wb.y,wb.z,wb.w};
            #pragma unroll
            for (int i = 0; i < 4; ++i)
                #pragma unroll
                for (int j = 0; j < 8; ++j)
                    a[i][j] += xr[i]*wr[j];
        }
    }
    #pragma unroll
    for (int i = 0; i < 4; ++i) {
        int n = m0g + m0 + i;
        float dv = dinv[n];
        float4 v0 = make_float4(a[i][0]*dv, a[i][1]*dv, a[i][2]*dv, a[i][3]*dv);
        float4 v1 = make_float4(a[i][4]*dv, a[i][5]*dv, a[i][6]*dv, a[i][7]*dv);
        *(float4*)&hs[(size_t)n*HID + j0]      = v0;
        *(float4*)&hs[(size_t)n*HID + 64 + j0] = v1;
    }
}

// layer-2 gather agg over a 64-feature half; per-graph half-slab 2.56MB fits XCD L2
__global__ __launch_bounds__(256) void k_agg2(
        const int* __restrict__ rowStart, const int* __restrict__ csrSrc,
        const float* __restrict__ hs, const float* __restrict__ dinv,
        const float* __restrict__ bias, float* __restrict__ out, int half) {
    int g = blockIdx.x;
    int graph = g & 7;
    int i = g >> 3;                         // 0..1249
    int n = graph*NN + i*8 + (threadIdx.x >> 5);
    int lane = threadIdx.x & 31;
    int col = half*32 + lane;               // float2 column
    const float2* hp = (const float2*)hs;
    float2 acc = hp[(size_t)n*64 + col];    // self-loop message
    int beg = rowStart[n], end = rowStart[n+1];
    for (int e = beg; e < end; e += 32) {
        int m = end - e; if (m > 32) m = 32;
        int s = (lane < m) ? csrSrc[e + lane] : 0;
        for (int j = 0; j < m; ++j) {
            int sj = __shfl(s, j, 32);
            float2 v = hp[(size_t)sj*64 + col];
            acc.x += v.x; acc.y += v.y;
        }
    }
    float dv = dinv[n];
    float2 bb = ((const float2*)bias)[col];
    float2 o;
    o.x = fmaxf(acc.x*dv + bb.x, 0.0f);
    o.y = fmaxf(acc.y*dv + bb.y, 0.0f);
    ((float2*)out)[(size_t)n*64 + col] = o;
}

// MLP1: block per (batch, 16-output group); 16 lanes per output, shuffle-reduce.
__global__ __launch_bounds__(256) void k_mlp1(
        const float* __restrict__ x, const int* __restrict__ avail,
        const int* __restrict__ pos, const float* __restrict__ actions,
        const float* __restrict__ steps,
        const float* __restrict__ Wp1, const float* __restrict__ bp1,
        float* __restrict__ hm) {
    int b  = blockIdx.x >> 4;
    int jg = blockIdx.x & 15;
    int t  = threadIdx.x;
    __shared__ float c[PROJ_IN];
    __shared__ int p[5];
    if (t < 4) p[t] = avail[b*4 + t] + b*NN;
    if (t == 4) p[4] = pos[b] + b*NN;
    __syncthreads();
    for (int i = t; i < 5*HID; i += 256)
        c[i] = x[(size_t)p[i >> 7]*HID + (i & 127)];
    if (t < ALAST) c[5*HID + t] = actions[b*ALAST + t];
    if (t == ALAST) c[5*HID + ALAST] = steps[b];
    __syncthreads();
    int o = t >> 4, sub = t & 15;
    int j = jg*16 + o;
    const float* wr = Wp1 + (size_t)j*PROJ_IN;
    float s = 0.f;
    for (int k = sub; k < PROJ_IN; k += 16) s += c[k]*wr[k];
    #pragma unroll
    for (int d = 8; d; d >>= 1) s += __shfl_down(s, d, 16);
    if (sub == 0) hm[b*EMB + j] = fmaxf(s + bp1[j], 0.f);
}

// MLP2: block per (batch, 16-output group); 16 lanes per output, shuffle-reduce.
__global__ __launch_bounds__(256) void k_mlp2(
        const float* __restrict__ hm, const float* __restrict__ Wp2,
        const float* __restrict__ bp2, float* __restrict__ out) {
    int b  = blockIdx.x >> 4;
    int jg = blockIdx.x & 15;
    int t  = threadIdx.x;
    __shared__ float c[EMB];
    if (t < EMB) c[t] = hm[b*EMB + t];
    __syncthreads();
    int o = t >> 4, sub = t & 15;
    int j = jg*16 + o;
    const float* wr = Wp2 + (size_t)j*EMB;
    float s = 0.f;
    for (int k = sub; k < EMB; k += 16) s += c[k]*wr[k];
    #pragma unroll
    for (int d = 8; d; d >>= 1) s += __shfl_down(s, d, 16);
    if (sub == 0) out[b*EMB + j] = s + bp2[j];
}

extern "C" void kernel_launch(void* const* d_in, const int* in_sizes, int n_in,
                              void* d_out, int out_size, void* d_ws, size_t ws_size,
                              hipStream_t stream) {
    const float* graph_x = (const float*)d_in[0];
    const int*   edges   = (const int*)d_in[1];
    const int*   pos     = (const int*)d_in[2];
    const int*   avail   = (const int*)d_in[3];
    const float* actions = (const float*)d_in[4];
    const float* steps   = (const float*)d_in[5];
    const float* W1  = (const float*)d_in[6];
    const float* b1  = (const float*)d_in[7];
    const float* W2  = (const float*)d_in[8];
    const float* b2  = (const float*)d_in[9];
    const float* Wp1 = (const float*)d_in[10];
    const float* bp1 = (const float*)d_in[11];
    const float* Wp2 = (const float*)d_in[12];
    const float* bp2 = (const float*)d_in[13];
    float* out = (float*)d_out;

    char* ws = (char*)d_ws;
    size_t off = 0;
    #define ALLOC(ptrname, type, nelem) \
        type* ptrname = (type*)(ws + off); off = (off + (size_t)(nelem)*sizeof(type) + 255) & ~(size_t)255;
    ALLOC(cnt,      int,   NNODES)
    ALLOC(rowStart, int,   NNODES+1)
    ALLOC(bsum,     int,   512)
    ALLOC(hist,     int,   (size_t)NB*GB*NN)     // per-block histograms / offsets
    ALLOC(rankL,    int,   NEDGE)
    ALLOC(csrSrc,   int,   NEDGE)
    ALLOC(dinv,     float, NNODES)
    ALLOC(xs5,      float, (size_t)NNODES*FIN)   // SoA prescaled input
    ALLOC(ax,       float, (size_t)NNODES*FIN)   // aggregated 5-dim
    ALLOC(bufA,     float, (size_t)NNODES*HID)   // hs (layer-2 staging)
    ALLOC(bufC,     float, (size_t)NNODES*HID)   // layer-2 output
    ALLOC(hm,       float, (size_t)NB*EMB)
    #undef ALLOC

    // CSR build: LDS histograms, no global atomics
    k_histL<<<NB*GB, 256, 0, stream>>>(edges, hist, rankL);
    k_scanB<<<NBLK, 256, 0, stream>>>(hist, cnt);
    k_scan1<<<NBLK, 256, 0, stream>>>(cnt, rowStart, bsum);
    k_scan2<<<1, 512, 0, stream>>>(bsum);
    k_scan3<<<NBLK, 256, 0, stream>>>(rowStart, bsum, cnt, dinv, graph_x, xs5);
    k_fillL<<<NB*GB, 256, 0, stream>>>(edges, rowStart, hist, rankL, csrSrc);

    // layer 1 aggregation on 5-dim raw features
    k_agg5<<<8*((NN+255)/256), 256, 0, stream>>>(rowStart, csrSrc, xs5, dinv, ax);

    // fused layer-1 dense + layer-2 dense
    k_h12<<<NNODES/64, 256, 0, stream>>>(ax, W1, b1, W2, dinv, bufA);

    // layer-2 aggregation per 64-feature half
    k_agg2<<<NNODES/8, 256, 0, stream>>>(rowStart, csrSrc, bufA, dinv, b2, bufC, 0);
    k_agg2<<<NNODES/8, 256, 0, stream>>>(rowStart, csrSrc, bufA, dinv, b2, bufC, 1);

    // head
    k_mlp1<<<NB*16, 256, 0, stream>>>(bufC, avail, pos, actions, steps, Wp1, bp1, hm);
    k_mlp2<<<NB*16, 256, 0, stream>>>(hm, Wp2, bp2, out);
}

// Round 10
// 271.798 us; speedup vs baseline: 1.6730x; 1.6730x over previous
//
#include <hip/hip_runtime.h>

#define NB 8
#define NN 10000
#define NE 160000
#define NNODES (NB*NN)          // 80000
#define NEDGE (NB*NE)           // 1280000
#define FIN 5
#define HID 128
#define EMB 256
#define ALAST 10
#define PROJ_IN (HID*5 + ALAST + 1)  // 651
#define NBLK ((NNODES+255)/256)      // 313
#define GB 32                        // blocks per graph for CSR build
#define EPB (NE/GB)                  // 5000 edges per block

// ---- CSR build, no global atomics ----
__global__ __launch_bounds__(256) void k_histL(const int* __restrict__ edges,
                                               int* __restrict__ hist,
                                               int* __restrict__ rankL) {
    int g = blockIdx.x & 7;                 // XCD pin
    int b = blockIdx.x >> 3;                // 0..GB-1
    __shared__ __align__(16) int c[NN];
    int4* c4 = (int4*)c;
    for (int i = threadIdx.x; i < NN/4; i += 256) c4[i] = make_int4(0,0,0,0);
    __syncthreads();
    const int* dstp = edges + (size_t)g*2*NE + NE + b*EPB;
    int* rl = rankL + (size_t)g*NE + b*EPB;
    const int4* d4p = (const int4*)dstp;
    for (int i = threadIdx.x; i < EPB/4; i += 256) {
        int4 d4 = d4p[i];
        int e0 = 4*i;
        rl[e0+0] = atomicAdd(&c[d4.x], 1);
        rl[e0+1] = atomicAdd(&c[d4.y], 1);
        rl[e0+2] = atomicAdd(&c[d4.z], 1);
        rl[e0+3] = atomicAdd(&c[d4.w], 1);
    }
    __syncthreads();
    int4* hp = (int4*)(hist + (size_t)(g*GB + b)*NN);
    for (int i = threadIdx.x; i < NN/4; i += 256) hp[i] = c4[i];
}

// fused: per-dst prefix across GB block-hists (leaves block offsets in hist,
// emits cnt) + block-level exclusive scan of counts -> rowStart, bsum.
__global__ void k_scan1(int* __restrict__ hist, int* __restrict__ cnt,
                        int* __restrict__ rowStart, int* __restrict__ bsum) {
    __shared__ int sh[256];
    int tid = threadIdx.x;
    int i = blockIdx.x*256 + tid;
    int run = 0;
    if (i < NNODES) {
        int g = i / NN, dl = i - g*NN;
        int* hbase = hist + (size_t)g*GB*NN + dl;
        #pragma unroll
        for (int b = 0; b < GB; ++b) {
            int v = hbase[(size_t)b*NN];
            hbase[(size_t)b*NN] = run;      // exclusive within-dst offset
            run += v;
        }
        cnt[i] = run;
    }
    sh[tid] = run;
    __syncthreads();
    for (int off = 1; off < 256; off <<= 1) {
        int t = (tid >= off) ? sh[tid - off] : 0;
        __syncthreads();
        sh[tid] += t;
        __syncthreads();
    }
    if (i < NNODES) rowStart[i] = sh[tid] - run;        // exclusive
    if (tid == 255) bsum[blockIdx.x] = sh[255];
}

__global__ void k_scan2(int* bsum) {
    __shared__ int sh[512];
    int tid = threadIdx.x;
    int v = (tid < NBLK) ? bsum[tid] : 0;
    sh[tid] = v;
    __syncthreads();
    for (int off = 1; off < 512; off <<= 1) {
        int t = (tid >= off) ? sh[tid - off] : 0;
        __syncthreads();
        sh[tid] += t;
        __syncthreads();
    }
    if (tid < NBLK) bsum[tid] = sh[tid] - v;            // exclusive
}

// add block offsets; compute dinv; prescale 5-dim features into SoA xs5
__global__ void k_scan3(int* __restrict__ rowStart, const int* __restrict__ bsum,
                        const int* __restrict__ cnt, float* __restrict__ dinv,
                        const float* __restrict__ x, float* __restrict__ xs5) {
    int i = blockIdx.x*256 + threadIdx.x;
    if (i < NNODES) {
        rowStart[i] = rowStart[i] + bsum[blockIdx.x];
        float dv = rsqrtf(1.0f + (float)cnt[i]);        // +1 = self loop
        dinv[i] = dv;
        #pragma unroll
        for (int f = 0; f < FIN; ++f)
            xs5[f*NNODES + i] = x[(size_t)i*FIN + f] * dv;
    }
    if (i == 0) rowStart[NNODES] = NEDGE;
}

// p = rowStart[dst] + blockOffset[b][dst] + rank_local[e]; plain stores only.
__global__ __launch_bounds__(256) void k_fillL(const int* __restrict__ edges,
                                               const int* __restrict__ rowStart,
                                               const int* __restrict__ hist,
                                               const int* __restrict__ rankL,
                                               int* __restrict__ csrSrc) {
    int g = blockIdx.x & 7;
    int b = blockIdx.x >> 3;
    const int* base = edges + (size_t)g*2*NE;
    const int4* s4p = (const int4*)(base + b*EPB);
    const int4* d4p = (const int4*)(base + NE + b*EPB);
    const int4* r4p = (const int4*)(rankL + (size_t)g*NE + b*EPB);
    const int* rs = rowStart + g*NN;
    const int* ho = hist + (size_t)(g*GB + b)*NN;
    int gofs = g*NN;
    for (int i = threadIdx.x; i < EPB/4; i += 256) {
        int4 s4 = s4p[i];
        int4 d4 = d4p[i];
        int4 r4 = r4p[i];
        csrSrc[rs[d4.x] + ho[d4.x] + r4.x] = s4.x + gofs;
        csrSrc[rs[d4.y] + ho[d4.y] + r4.y] = s4.y + gofs;
        csrSrc[rs[d4.z] + ho[d4.z] + r4.z] = s4.z + gofs;
        csrSrc[rs[d4.w] + ho[d4.w] + r4.w] = s4.w + gofs;
    }
}

// layer-1 aggregation on the 5 raw features (agg commutes with dense transform).
__global__ __launch_bounds__(256) void k_agg5(
        const int* __restrict__ rowStart, const int* __restrict__ csrSrc,
        const float* __restrict__ xs5, const float* __restrict__ dinv,
        float* __restrict__ ax) {
    int g = blockIdx.x;
    int graph = g & 7;
    int nl = (g >> 3)*256 + threadIdx.x;
    if (nl >= NN) return;
    int n = graph*NN + nl;
    float a0 = xs5[0*NNODES + n], a1 = xs5[1*NNODES + n], a2 = xs5[2*NNODES + n],
          a3 = xs5[3*NNODES + n], a4 = xs5[4*NNODES + n];
    int beg = rowStart[n], end = rowStart[n+1];
    for (int e = beg; e < end; ++e) {
        int s = csrSrc[e];
        a0 += xs5[0*NNODES + s];
        a1 += xs5[1*NNODES + s];
        a2 += xs5[2*NNODES + s];
        a3 += xs5[3*NNODES + s];
        a4 += xs5[4*NNODES + s];
    }
    float dv = dinv[n];
    ax[(size_t)n*FIN + 0] = a0*dv;
    ax[(size_t)n*FIN + 1] = a1*dv;
    ax[(size_t)n*FIN + 2] = a2*dv;
    ax[(size_t)n*FIN + 3] = a3*dv;
    ax[(size_t)n*FIN + 4] = a4*dv;
}

// Fused layer-1 dense + layer-2 dense (round-8 known-good: VGPR 80, 45us):
// H1 = relu(ax @ W1^T + b1) on the fly; hs = (H1 @ W2^T) * dinv.
// 128x128 tile, 8x8 per thread. 64x128 variant spilled to 256 VGPR -- do not.
#define KC 32
__global__ __launch_bounds__(256) void k_h12(
        const float* __restrict__ ax, const float* __restrict__ W1,
        const float* __restrict__ b1, const float* __restrict__ W2,
        const float* __restrict__ dinv, float* __restrict__ hs) {
    __shared__ float axs[FIN][128];
    __shared__ float w1s[FIN][128];
    __shared__ float b1s[128];
    __shared__ float xs[KC*128];
    __shared__ float wt[KC*128];
    int tid = threadIdx.x;
    int m0g = blockIdx.x * 128;
    if (tid < 128) {
        b1s[tid] = b1[tid];
        #pragma unroll
        for (int f = 0; f < FIN; ++f) w1s[f][tid] = W1[tid*FIN + f];
    } else {
        int r2 = tid - 128;
        #pragma unroll
        for (int f = 0; f < FIN; ++f) axs[f][r2] = ax[(size_t)(m0g + r2)*FIN + f];
    }
    int tx = tid & 15, ty = tid >> 4;
    int m0 = ty*8;
    int j0 = tx*4;
    int r  = tid >> 1;                  // staging row 0..127
    int kq = (tid & 1) * 16;            // staging k sub-chunk
    float a[8][8];
    #pragma unroll
    for (int i = 0; i < 8; ++i)
        #pragma unroll
        for (int j = 0; j < 8; ++j) a[i][j] = 0.f;
    __syncthreads();
    float axr[FIN];
    #pragma unroll
    for (int f = 0; f < FIN; ++f) axr[f] = axs[f][r];

    for (int kh = 0; kh < 128; kh += KC) {
        float4 wv[4];
        #pragma unroll
        for (int c = 0; c < 4; ++c)
            wv[c] = *(const float4*)&W2[(size_t)r*128 + kh + kq + 4*c];
        float hv[16];
        #pragma unroll
        for (int kk = 0; kk < 16; ++kk) {
            int k1 = kh + kq + kk;
            float sv = b1s[k1];
            #pragma unroll
            for (int f = 0; f < FIN; ++f) sv += axr[f]*w1s[f][k1];
            hv[kk] = fmaxf(sv, 0.0f);
        }
        __syncthreads();               // protect prev iter's reads
        #pragma unroll
        for (int kk = 0; kk < 16; ++kk) xs[(kq+kk)*128 + r] = hv[kk];
        #pragma unroll
        for (int c = 0; c < 4; ++c) {
            wt[(kq+4*c+0)*128 + r] = wv[c].x;
            wt[(kq+4*c+1)*128 + r] = wv[c].y;
            wt[(kq+4*c+2)*128 + r] = wv[c].z;
            wt[(kq+4*c+3)*128 + r] = wv[c].w;
        }
        __syncthreads();
        for (int k = 0; k < KC; ++k) {
            float4 xa = *(const float4*)&xs[k*128 + m0];
            float4 xb = *(const float4*)&xs[k*128 + m0 + 4];
            float4 wa = *(const float4*)&wt[k*128 + j0];
            float4 wb = *(const float4*)&wt[k*128 + j0 + 64];
            float xr[8] = {xa.x,xa.y,xa.z,xa.w,xb.x,xb.y,xb.z,xb.w};
            float wr[8] = {wa.x,wa.y,wa.z,wa.w,wb.x,wb.y,wb.z,wb.w};
            #pragma unroll
            for (int i = 0; i < 8; ++i)
                #pragma unroll
                for (int j = 0; j < 8; ++j)
                    a[i][j] += xr[i]*wr[j];
        }
    }
    #pragma unroll
    for (int i = 0; i < 8; ++i) {
        int n = m0g + m0 + i;
        float dv = dinv[n];
        float4 v0 = make_float4(a[i][0]*dv, a[i][1]*dv, a[i][2]*dv, a[i][3]*dv);
        float4 v1 = make_float4(a[i][4]*dv, a[i][5]*dv, a[i][6]*dv, a[i][7]*dv);
        *(float4*)&hs[(size_t)n*HID + j0]      = v0;
        *(float4*)&hs[(size_t)n*HID + 64 + j0] = v1;
    }
}

// layer-2 gather agg over a 64-feature half; 4-wide unrolled gathers for MLP.
__global__ __launch_bounds__(256) void k_agg2(
        const int* __restrict__ rowStart, const int* __restrict__ csrSrc,
        const float* __restrict__ hs, const float* __restrict__ dinv,
        const float* __restrict__ bias, float* __restrict__ out, int half) {
    int g = blockIdx.x;
    int graph = g & 7;
    int i = g >> 3;                         // 0..1249
    int n = graph*NN + i*8 + (threadIdx.x >> 5);
    int lane = threadIdx.x & 31;
    int col = half*32 + lane;               // float2 column
    const float2* hp = (const float2*)hs;
    float2 acc = hp[(size_t)n*64 + col];    // self-loop message
    int beg = rowStart[n], end = rowStart[n+1];
    for (int e = beg; e < end; e += 32) {
        int m = end - e; if (m > 32) m = 32;
        int s = (lane < m) ? csrSrc[e + lane] : 0;
        int j = 0;
        for (; j + 4 <= m; j += 4) {
            int s0 = __shfl(s, j+0, 32);
            int s1 = __shfl(s, j+1, 32);
            int s2 = __shfl(s, j+2, 32);
            int s3 = __shfl(s, j+3, 32);
            float2 v0 = hp[(size_t)s0*64 + col];
            float2 v1 = hp[(size_t)s1*64 + col];
            float2 v2 = hp[(size_t)s2*64 + col];
            float2 v3 = hp[(size_t)s3*64 + col];
            acc.x += (v0.x + v1.x) + (v2.x + v3.x);
            acc.y += (v0.y + v1.y) + (v2.y + v3.y);
        }
        for (; j < m; ++j) {
            int sj = __shfl(s, j, 32);
            float2 v = hp[(size_t)sj*64 + col];
            acc.x += v.x; acc.y += v.y;
        }
    }
    float dv = dinv[n];
    float2 bb = ((const float2*)bias)[col];
    float2 o;
    o.x = fmaxf(acc.x*dv + bb.x, 0.0f);
    o.y = fmaxf(acc.y*dv + bb.y, 0.0f);
    ((float2*)out)[(size_t)n*64 + col] = o;
}

// MLP1: block per (batch, 16-output group); 16 lanes per output, shuffle-reduce.
__global__ __launch_bounds__(256) void k_mlp1(
        const float* __restrict__ x, const int* __restrict__ avail,
        const int* __restrict__ pos, const float* __restrict__ actions,
        const float* __restrict__ steps,
        const float* __restrict__ Wp1, const float* __restrict__ bp1,
        float* __restrict__ hm) {
    int b  = blockIdx.x >> 4;
    int jg = blockIdx.x & 15;
    int t  = threadIdx.x;
    __shared__ float c[PROJ_IN];
    __shared__ int p[5];
    if (t < 4) p[t] = avail[b*4 + t] + b*NN;
    if (t == 4) p[4] = pos[b] + b*NN;
    __syncthreads();
    for (int i = t; i < 5*HID; i += 256)
        c[i] = x[(size_t)p[i >> 7]*HID + (i & 127)];
    if (t < ALAST) c[5*HID + t] = actions[b*ALAST + t];
    if (t == ALAST) c[5*HID + ALAST] = steps[b];
    __syncthreads();
    int o = t >> 4, sub = t & 15;
    int j = jg*16 + o;
    const float* wr = Wp1 + (size_t)j*PROJ_IN;
    float s = 0.f;
    for (int k = sub; k < PROJ_IN; k += 16) s += c[k]*wr[k];
    #pragma unroll
    for (int d = 8; d; d >>= 1) s += __shfl_down(s, d, 16);
    if (sub == 0) hm[b*EMB + j] = fmaxf(s + bp1[j], 0.f);
}

// MLP2: block per (batch, 16-output group); 16 lanes per output, shuffle-reduce.
__global__ __launch_bounds__(256) void k_mlp2(
        const float* __restrict__ hm, const float* __restrict__ Wp2,
        const float* __restrict__ bp2, float* __restrict__ out) {
    int b  = blockIdx.x >> 4;
    int jg = blockIdx.x & 15;
    int t  = threadIdx.x;
    __shared__ float c[EMB];
    if (t < EMB) c[t] = hm[b*EMB + t];
    __syncthreads();
    int o = t >> 4, sub = t & 15;
    int j = jg*16 + o;
    const float* wr = Wp2 + (size_t)j*EMB;
    float s = 0.f;
    for (int k = sub; k < EMB; k += 16) s += c[k]*wr[k];
    #pragma unroll
    for (int d = 8; d; d >>= 1) s += __shfl_down(s, d, 16);
    if (sub == 0) out[b*EMB + j] = s + bp2[j];
}

extern "C" void kernel_launch(void* const* d_in, const int* in_sizes, int n_in,
                              void* d_out, int out_size, void* d_ws, size_t ws_size,
                              hipStream_t stream) {
    const float* graph_x = (const float*)d_in[0];
    const int*   edges   = (const int*)d_in[1];
    const int*   pos     = (const int*)d_in[2];
    const int*   avail   = (const int*)d_in[3];
    const float* actions = (const float*)d_in[4];
    const float* steps   = (const float*)d_in[5];
    const float* W1  = (const float*)d_in[6];
    const float* b1  = (const float*)d_in[7];
    const float* W2  = (const float*)d_in[8];
    const float* b2  = (const float*)d_in[9];
    const float* Wp1 = (const float*)d_in[10];
    const float* bp1 = (const float*)d_in[11];
    const float* Wp2 = (const float*)d_in[12];
    const float* bp2 = (const float*)d_in[13];
    float* out = (float*)d_out;

    char* ws = (char*)d_ws;
    size_t off = 0;
    #define ALLOC(ptrname, type, nelem) \
        type* ptrname = (type*)(ws + off); off = (off + (size_t)(nelem)*sizeof(type) + 255) & ~(size_t)255;
    ALLOC(cnt,      int,   NNODES)
    ALLOC(rowStart, int,   NNODES+1)
    ALLOC(bsum,     int,   512)
    ALLOC(hist,     int,   (size_t)NB*GB*NN)     // per-block histograms / offsets
    ALLOC(rankL,    int,   NEDGE)
    ALLOC(csrSrc,   int,   NEDGE)
    ALLOC(dinv,     float, NNODES)
    ALLOC(xs5,      float, (size_t)NNODES*FIN)   // SoA prescaled input
    ALLOC(ax,       float, (size_t)NNODES*FIN)   // aggregated 5-dim
    ALLOC(bufA,     float, (size_t)NNODES*HID)   // hs (layer-2 staging)
    ALLOC(bufC,     float, (size_t)NNODES*HID)   // layer-2 output
    ALLOC(hm,       float, (size_t)NB*EMB)
    #undef ALLOC

    // CSR build: LDS histograms, no global atomics
    k_histL<<<NB*GB, 256, 0, stream>>>(edges, hist, rankL);
    k_scan1<<<NBLK, 256, 0, stream>>>(hist, cnt, rowStart, bsum);
    k_scan2<<<1, 512, 0, stream>>>(bsum);
    k_scan3<<<NBLK, 256, 0, stream>>>(rowStart, bsum, cnt, dinv, graph_x, xs5);
    k_fillL<<<NB*GB, 256, 0, stream>>>(edges, rowStart, hist, rankL, csrSrc);

    // layer 1 aggregation on 5-dim raw features
    k_agg5<<<8*((NN+255)/256), 256, 0, stream>>>(rowStart, csrSrc, xs5, dinv, ax);

    // fused layer-1 dense + layer-2 dense
    k_h12<<<NNODES/128, 256, 0, stream>>>(ax, W1, b1, W2, dinv, bufA);

    // layer-2 aggregation per 64-feature half
    k_agg2<<<NNODES/8, 256, 0, stream>>>(rowStart, csrSrc, bufA, dinv, b2, bufC, 0);
    k_agg2<<<NNODES/8, 256, 0, stream>>>(rowStart, csrSrc, bufA, dinv, b2, bufC, 1);

    // head
    k_mlp1<<<NB*16, 256, 0, stream>>>(bufC, avail, pos, actions, steps, Wp1, bp1, hm);
    k_mlp2<<<NB*16, 256, 0, stream>>>(hm, Wp2, bp2, out);
}

// Round 11
// 269.085 us; speedup vs baseline: 1.6899x; 1.0101x over previous
//
#include <hip/hip_runtime.h>

#define NB 8
#define NN 10000
#define NE 160000
#define NNODES (NB*NN)          // 80000
#define NEDGE (NB*NE)           // 1280000
#define FIN 5
#define HID 128
#define EMB 256
#define ALAST 10
#define PROJ_IN (HID*5 + ALAST + 1)  // 651
#define NBLK ((NNODES+255)/256)      // 313
#define GB 32                        // blocks per graph for CSR build
#define EPB (NE/GB)                  // 5000 edges per block

// ---- CSR build, no global atomics ----
__global__ __launch_bounds__(256) void k_histL(const int* __restrict__ edges,
                                               int* __restrict__ hist,
                                               int* __restrict__ rankL) {
    int g = blockIdx.x & 7;                 // XCD pin
    int b = blockIdx.x >> 3;                // 0..GB-1
    __shared__ __align__(16) int c[NN];
    int4* c4 = (int4*)c;
    for (int i = threadIdx.x; i < NN/4; i += 256) c4[i] = make_int4(0,0,0,0);
    __syncthreads();
    const int* dstp = edges + (size_t)g*2*NE + NE + b*EPB;
    int* rl = rankL + (size_t)g*NE + b*EPB;
    const int4* d4p = (const int4*)dstp;
    for (int i = threadIdx.x; i < EPB/4; i += 256) {
        int4 d4 = d4p[i];
        int e0 = 4*i;
        rl[e0+0] = atomicAdd(&c[d4.x], 1);
        rl[e0+1] = atomicAdd(&c[d4.y], 1);
        rl[e0+2] = atomicAdd(&c[d4.z], 1);
        rl[e0+3] = atomicAdd(&c[d4.w], 1);
    }
    __syncthreads();
    int4* hp = (int4*)(hist + (size_t)(g*GB + b)*NN);
    for (int i = threadIdx.x; i < NN/4; i += 256) hp[i] = c4[i];
}

// fused: per-dst prefix across GB block-hists (leaves block offsets in hist,
// emits cnt) + block-level exclusive scan of counts -> rowStart, bsum.
__global__ void k_scan1(int* __restrict__ hist, int* __restrict__ cnt,
                        int* __restrict__ rowStart, int* __restrict__ bsum) {
    __shared__ int sh[256];
    int tid = threadIdx.x;
    int i = blockIdx.x*256 + tid;
    int run = 0;
    if (i < NNODES) {
        int g = i / NN, dl = i - g*NN;
        int* hbase = hist + (size_t)g*GB*NN + dl;
        #pragma unroll
        for (int b = 0; b < GB; ++b) {
            int v = hbase[(size_t)b*NN];
            hbase[(size_t)b*NN] = run;      // exclusive within-dst offset
            run += v;
        }
        cnt[i] = run;
    }
    sh[tid] = run;
    __syncthreads();
    for (int off = 1; off < 256; off <<= 1) {
        int t = (tid >= off) ? sh[tid - off] : 0;
        __syncthreads();
        sh[tid] += t;
        __syncthreads();
    }
    if (i < NNODES) rowStart[i] = sh[tid] - run;        // exclusive
    if (tid == 255) bsum[blockIdx.x] = sh[255];
}

__global__ void k_scan2(int* bsum) {
    __shared__ int sh[512];
    int tid = threadIdx.x;
    int v = (tid < NBLK) ? bsum[tid] : 0;
    sh[tid] = v;
    __syncthreads();
    for (int off = 1; off < 512; off <<= 1) {
        int t = (tid >= off) ? sh[tid - off] : 0;
        __syncthreads();
        sh[tid] += t;
        __syncthreads();
    }
    if (tid < NBLK) bsum[tid] = sh[tid] - v;            // exclusive
}

// add block offsets; compute dinv; prescale 5-dim features into SoA xs5
__global__ void k_scan3(int* __restrict__ rowStart, const int* __restrict__ bsum,
                        const int* __restrict__ cnt, float* __restrict__ dinv,
                        const float* __restrict__ x, float* __restrict__ xs5) {
    int i = blockIdx.x*256 + threadIdx.x;
    if (i < NNODES) {
        rowStart[i] = rowStart[i] + bsum[blockIdx.x];
        float dv = rsqrtf(1.0f + (float)cnt[i]);        // +1 = self loop
        dinv[i] = dv;
        #pragma unroll
        for (int f = 0; f < FIN; ++f)
            xs5[f*NNODES + i] = x[(size_t)i*FIN + f] * dv;
    }
    if (i == 0) rowStart[NNODES] = NEDGE;
}

// p = rowStart[dst] + blockOffset[b][dst] + rank_local[e]; plain stores only.
__global__ __launch_bounds__(256) void k_fillL(const int* __restrict__ edges,
                                               const int* __restrict__ rowStart,
                                               const int* __restrict__ hist,
                                               const int* __restrict__ rankL,
                                               int* __restrict__ csrSrc) {
    int g = blockIdx.x & 7;
    int b = blockIdx.x >> 3;
    const int* base = edges + (size_t)g*2*NE;
    const int4* s4p = (const int4*)(base + b*EPB);
    const int4* d4p = (const int4*)(base + NE + b*EPB);
    const int4* r4p = (const int4*)(rankL + (size_t)g*NE + b*EPB);
    const int* rs = rowStart + g*NN;
    const int* ho = hist + (size_t)(g*GB + b)*NN;
    int gofs = g*NN;
    for (int i = threadIdx.x; i < EPB/4; i += 256) {
        int4 s4 = s4p[i];
        int4 d4 = d4p[i];
        int4 r4 = r4p[i];
        csrSrc[rs[d4.x] + ho[d4.x] + r4.x] = s4.x + gofs;
        csrSrc[rs[d4.y] + ho[d4.y] + r4.y] = s4.y + gofs;
        csrSrc[rs[d4.z] + ho[d4.z] + r4.z] = s4.z + gofs;
        csrSrc[rs[d4.w] + ho[d4.w] + r4.w] = s4.w + gofs;
    }
}

// layer-1 aggregation on the 5 raw features (agg commutes with dense transform).
__global__ __launch_bounds__(256) void k_agg5(
        const int* __restrict__ rowStart, const int* __restrict__ csrSrc,
        const float* __restrict__ xs5, const float* __restrict__ dinv,
        float* __restrict__ ax) {
    int g = blockIdx.x;
    int graph = g & 7;
    int nl = (g >> 3)*256 + threadIdx.x;
    if (nl >= NN) return;
    int n = graph*NN + nl;
    float a0 = xs5[0*NNODES + n], a1 = xs5[1*NNODES + n], a2 = xs5[2*NNODES + n],
          a3 = xs5[3*NNODES + n], a4 = xs5[4*NNODES + n];
    int beg = rowStart[n], end = rowStart[n+1];
    for (int e = beg; e < end; ++e) {
        int s = csrSrc[e];
        a0 += xs5[0*NNODES + s];
        a1 += xs5[1*NNODES + s];
        a2 += xs5[2*NNODES + s];
        a3 += xs5[3*NNODES + s];
        a4 += xs5[4*NNODES + s];
    }
    float dv = dinv[n];
    ax[(size_t)n*FIN + 0] = a0*dv;
    ax[(size_t)n*FIN + 1] = a1*dv;
    ax[(size_t)n*FIN + 2] = a2*dv;
    ax[(size_t)n*FIN + 3] = a3*dv;
    ax[(size_t)n*FIN + 4] = a4*dv;
}

// Fused layer-1 dense + layer-2 dense, column-split for occupancy:
// block = 128 rows x 64 cols (jb = blockIdx&1 picks the column half), grid 1250.
// H1 staging identical to the round-8 known-good kernel (VGPR 80); only the
// W2 stage/accumulator shrink. 64x128 ROW-split spilled to 256 VGPR -- avoid.
#define KC 32
__global__ __launch_bounds__(256) void k_h12(
        const float* __restrict__ ax, const float* __restrict__ W1,
        const float* __restrict__ b1, const float* __restrict__ W2,
        const float* __restrict__ dinv, float* __restrict__ hs) {
    __shared__ float axs[FIN][128];
    __shared__ float w1s[FIN][128];
    __shared__ float b1s[128];
    __shared__ float xs[KC*128];
    __shared__ float wt[KC*64];
    int tid = threadIdx.x;
    int jb  = blockIdx.x & 1;               // column half: j in [jb*64, jb*64+64)
    int m0g = (blockIdx.x >> 1) * 128;
    if (tid < 128) {
        b1s[tid] = b1[tid];
        #pragma unroll
        for (int f = 0; f < FIN; ++f) w1s[f][tid] = W1[tid*FIN + f];
    } else {
        int r2 = tid - 128;
        #pragma unroll
        for (int f = 0; f < FIN; ++f) axs[f][r2] = ax[(size_t)(m0g + r2)*FIN + f];
    }
    int tx = tid & 15, ty = tid >> 4;
    int m0 = ty*8;                      // 16 groups x 8 rows = 128
    int j0 = tx*4;                      // 16 groups x 4 cols = 64
    int r  = tid >> 1;                  // H1 staging row 0..127
    int kq = (tid & 1) * 16;            // H1 staging k sub-chunk
    int rw  = tid >> 2;                 // W2 staging local col 0..63
    int kqw = (tid & 3) * 8;            // W2 staging k sub-chunk
    float a[8][4];
    #pragma unroll
    for (int i = 0; i < 8; ++i)
        #pragma unroll
        for (int j = 0; j < 4; ++j) a[i][j] = 0.f;
    __syncthreads();
    float axr[FIN];
    #pragma unroll
    for (int f = 0; f < FIN; ++f) axr[f] = axs[f][r];

    for (int kh = 0; kh < 128; kh += KC) {
        float4 wv0 = *(const float4*)&W2[(size_t)(jb*64 + rw)*128 + kh + kqw];
        float4 wv1 = *(const float4*)&W2[(size_t)(jb*64 + rw)*128 + kh + kqw + 4];
        float hv[16];
        #pragma unroll
        for (int kk = 0; kk < 16; ++kk) {
            int k1 = kh + kq + kk;
            float sv = b1s[k1];
            #pragma unroll
            for (int f = 0; f < FIN; ++f) sv += axr[f]*w1s[f][k1];
            hv[kk] = fmaxf(sv, 0.0f);
        }
        __syncthreads();               // protect prev iter's reads
        #pragma unroll
        for (int kk = 0; kk < 16; ++kk) xs[(kq+kk)*128 + r] = hv[kk];
        wt[(kqw+0)*64 + rw] = wv0.x;
        wt[(kqw+1)*64 + rw] = wv0.y;
        wt[(kqw+2)*64 + rw] = wv0.z;
        wt[(kqw+3)*64 + rw] = wv0.w;
        wt[(kqw+4)*64 + rw] = wv1.x;
        wt[(kqw+5)*64 + rw] = wv1.y;
        wt[(kqw+6)*64 + rw] = wv1.z;
        wt[(kqw+7)*64 + rw] = wv1.w;
        __syncthreads();
        for (int k = 0; k < KC; ++k) {
            float4 xa = *(const float4*)&xs[k*128 + m0];
            float4 xb = *(const float4*)&xs[k*128 + m0 + 4];
            float4 wa = *(const float4*)&wt[k*64 + j0];
            float xr[8] = {xa.x,xa.y,xa.z,xa.w,xb.x,xb.y,xb.z,xb.w};
            #pragma unroll
            for (int i = 0; i < 8; ++i) {
                a[i][0] += xr[i]*wa.x;
                a[i][1] += xr[i]*wa.y;
                a[i][2] += xr[i]*wa.z;
                a[i][3] += xr[i]*wa.w;
            }
        }
    }
    #pragma unroll
    for (int i = 0; i < 8; ++i) {
        int n = m0g + m0 + i;
        float dv = dinv[n];
        float4 v0 = make_float4(a[i][0]*dv, a[i][1]*dv, a[i][2]*dv, a[i][3]*dv);
        *(float4*)&hs[(size_t)n*HID + jb*64 + j0] = v0;
    }
}

// layer-2 gather agg over a 64-feature half; 4-wide unrolled gathers for MLP.
__global__ __launch_bounds__(256) void k_agg2(
        const int* __restrict__ rowStart, const int* __restrict__ csrSrc,
        const float* __restrict__ hs, const float* __restrict__ dinv,
        const float* __restrict__ bias, float* __restrict__ out, int half) {
    int g = blockIdx.x;
    int graph = g & 7;
    int i = g >> 3;                         // 0..1249
    int n = graph*NN + i*8 + (threadIdx.x >> 5);
    int lane = threadIdx.x & 31;
    int col = half*32 + lane;               // float2 column
    const float2* hp = (const float2*)hs;
    float2 acc = hp[(size_t)n*64 + col];    // self-loop message
    int beg = rowStart[n], end = rowStart[n+1];
    for (int e = beg; e < end; e += 32) {
        int m = end - e; if (m > 32) m = 32;
        int s = (lane < m) ? csrSrc[e + lane] : 0;
        int j = 0;
        for (; j + 4 <= m; j += 4) {
            int s0 = __shfl(s, j+0, 32);
            int s1 = __shfl(s, j+1, 32);
            int s2 = __shfl(s, j+2, 32);
            int s3 = __shfl(s, j+3, 32);
            float2 v0 = hp[(size_t)s0*64 + col];
            float2 v1 = hp[(size_t)s1*64 + col];
            float2 v2 = hp[(size_t)s2*64 + col];
            float2 v3 = hp[(size_t)s3*64 + col];
            acc.x += (v0.x + v1.x) + (v2.x + v3.x);
            acc.y += (v0.y + v1.y) + (v2.y + v3.y);
        }
        for (; j < m; ++j) {
            int sj = __shfl(s, j, 32);
            float2 v = hp[(size_t)sj*64 + col];
            acc.x += v.x; acc.y += v.y;
        }
    }
    float dv = dinv[n];
    float2 bb = ((const float2*)bias)[col];
    float2 o;
    o.x = fmaxf(acc.x*dv + bb.x, 0.0f);
    o.y = fmaxf(acc.y*dv + bb.y, 0.0f);
    ((float2*)out)[(size_t)n*64 + col] = o;
}

// MLP1: block per (batch, 16-output group); 16 lanes per output, shuffle-reduce.
__global__ __launch_bounds__(256) void k_mlp1(
        const float* __restrict__ x, const int* __restrict__ avail,
        const int* __restrict__ pos, const float* __restrict__ actions,
        const float* __restrict__ steps,
        const float* __restrict__ Wp1, const float* __restrict__ bp1,
        float* __restrict__ hm) {
    int b  = blockIdx.x >> 4;
    int jg = blockIdx.x & 15;
    int t  = threadIdx.x;
    __shared__ float c[PROJ_IN];
    __shared__ int p[5];
    if (t < 4) p[t] = avail[b*4 + t] + b*NN;
    if (t == 4) p[4] = pos[b] + b*NN;
    __syncthreads();
    for (int i = t; i < 5*HID; i += 256)
        c[i] = x[(size_t)p[i >> 7]*HID + (i & 127)];
    if (t < ALAST) c[5*HID + t] = actions[b*ALAST + t];
    if (t == ALAST) c[5*HID + ALAST] = steps[b];
    __syncthreads();
    int o = t >> 4, sub = t & 15;
    int j = jg*16 + o;
    const float* wr = Wp1 + (size_t)j*PROJ_IN;
    float s = 0.f;
    for (int k = sub; k < PROJ_IN; k += 16) s += c[k]*wr[k];
    #pragma unroll
    for (int d = 8; d; d >>= 1) s += __shfl_down(s, d, 16);
    if (sub == 0) hm[b*EMB + j] = fmaxf(s + bp1[j], 0.f);
}

// MLP2: block per (batch, 16-output group); 16 lanes per output, shuffle-reduce.
__global__ __launch_bounds__(256) void k_mlp2(
        const float* __restrict__ hm, const float* __restrict__ Wp2,
        const float* __restrict__ bp2, float* __restrict__ out) {
    int b  = blockIdx.x >> 4;
    int jg = blockIdx.x & 15;
    int t  = threadIdx.x;
    __shared__ float c[EMB];
    if (t < EMB) c[t] = hm[b*EMB + t];
    __syncthreads();
    int o = t >> 4, sub = t & 15;
    int j = jg*16 + o;
    const float* wr = Wp2 + (size_t)j*EMB;
    float s = 0.f;
    for (int k = sub; k < EMB; k += 16) s += c[k]*wr[k];
    #pragma unroll
    for (int d = 8; d; d >>= 1) s += __shfl_down(s, d, 16);
    if (sub == 0) out[b*EMB + j] = s + bp2[j];
}

extern "C" void kernel_launch(void* const* d_in, const int* in_sizes, int n_in,
                              void* d_out, int out_size, void* d_ws, size_t ws_size,
                              hipStream_t stream) {
    const float* graph_x = (const float*)d_in[0];
    const int*   edges   = (const int*)d_in[1];
    const int*   pos     = (const int*)d_in[2];
    const int*   avail   = (const int*)d_in[3];
    const float* actions = (const float*)d_in[4];
    const float* steps   = (const float*)d_in[5];
    const float* W1  = (const float*)d_in[6];
    const float* b1  = (const float*)d_in[7];
    const float* W2  = (const float*)d_in[8];
    const float* b2  = (const float*)d_in[9];
    const float* Wp1 = (const float*)d_in[10];
    const float* bp1 = (const float*)d_in[11];
    const float* Wp2 = (const float*)d_in[12];
    const float* bp2 = (const float*)d_in[13];
    float* out = (float*)d_out;

    char* ws = (char*)d_ws;
    size_t off = 0;
    #define ALLOC(ptrname, type, nelem) \
        type* ptrname = (type*)(ws + off); off = (off + (size_t)(nelem)*sizeof(type) + 255) & ~(size_t)255;
    ALLOC(cnt,      int,   NNODES)
    ALLOC(rowStart, int,   NNODES+1)
    ALLOC(bsum,     int,   512)
    ALLOC(hist,     int,   (size_t)NB*GB*NN)     // per-block histograms / offsets
    ALLOC(rankL,    int,   NEDGE)
    ALLOC(csrSrc,   int,   NEDGE)
    ALLOC(dinv,     float, NNODES)
    ALLOC(xs5,      float, (size_t)NNODES*FIN)   // SoA prescaled input
    ALLOC(ax,       float, (size_t)NNODES*FIN)   // aggregated 5-dim
    ALLOC(bufA,     float, (size_t)NNODES*HID)   // hs (layer-2 staging)
    ALLOC(bufC,     float, (size_t)NNODES*HID)   // layer-2 output
    ALLOC(hm,       float, (size_t)NB*EMB)
    #undef ALLOC

    // CSR build: LDS histograms, no global atomics
    k_histL<<<NB*GB, 256, 0, stream>>>(edges, hist, rankL);
    k_scan1<<<NBLK, 256, 0, stream>>>(hist, cnt, rowStart, bsum);
    k_scan2<<<1, 512, 0, stream>>>(bsum);
    k_scan3<<<NBLK, 256, 0, stream>>>(rowStart, bsum, cnt, dinv, graph_x, xs5);
    k_fillL<<<NB*GB, 256, 0, stream>>>(edges, rowStart, hist, rankL, csrSrc);

    // layer 1 aggregation on 5-dim raw features
    k_agg5<<<8*((NN+255)/256), 256, 0, stream>>>(rowStart, csrSrc, xs5, dinv, ax);

    // fused layer-1 dense + layer-2 dense (column-split, grid 1250)
    k_h12<<<(NNODES/128)*2, 256, 0, stream>>>(ax, W1, b1, W2, dinv, bufA);

    // layer-2 aggregation per 64-feature half
    k_agg2<<<NNODES/8, 256, 0, stream>>>(rowStart, csrSrc, bufA, dinv, b2, bufC, 0);
    k_agg2<<<NNODES/8, 256, 0, stream>>>(rowStart, csrSrc, bufA, dinv, b2, bufC, 1);

    // head
    k_mlp1<<<NB*16, 256, 0, stream>>>(bufC, avail, pos, actions, steps, Wp1, bp1, hm);
    k_mlp2<<<NB*16, 256, 0, stream>>>(hm, Wp2, bp2, out);
}

// Round 12
// 217.658 us; speedup vs baseline: 2.0892x; 1.2363x over previous
//
#include <hip/hip_runtime.h>

#define NB 8
#define NN 10000
#define NE 160000
#define NNODES (NB*NN)          // 80000
#define NEDGE (NB*NE)           // 1280000
#define FIN 5
#define HID 128
#define EMB 256
#define ALAST 10
#define PROJ_IN (HID*5 + ALAST + 1)  // 651
#define NBLK ((NNODES+255)/256)      // 313
#define GB 32                        // blocks per graph for CSR build
#define EPB (NE/GB)                  // 5000 edges per block

// ---- CSR build, no global atomics ----
__global__ __launch_bounds__(256) void k_histL(const int* __restrict__ edges,
                                               int* __restrict__ hist,
                                               int* __restrict__ rankL) {
    int g = blockIdx.x & 7;                 // XCD pin
    int b = blockIdx.x >> 3;                // 0..GB-1
    __shared__ __align__(16) int c[NN];
    int4* c4 = (int4*)c;
    for (int i = threadIdx.x; i < NN/4; i += 256) c4[i] = make_int4(0,0,0,0);
    __syncthreads();
    const int* dstp = edges + (size_t)g*2*NE + NE + b*EPB;
    int* rl = rankL + (size_t)g*NE + b*EPB;
    const int4* d4p = (const int4*)dstp;
    for (int i = threadIdx.x; i < EPB/4; i += 256) {
        int4 d4 = d4p[i];
        int e0 = 4*i;
        rl[e0+0] = atomicAdd(&c[d4.x], 1);
        rl[e0+1] = atomicAdd(&c[d4.y], 1);
        rl[e0+2] = atomicAdd(&c[d4.z], 1);
        rl[e0+3] = atomicAdd(&c[d4.w], 1);
    }
    __syncthreads();
    int4* hp = (int4*)(hist + (size_t)(g*GB + b)*NN);
    for (int i = threadIdx.x; i < NN/4; i += 256) hp[i] = c4[i];
}

// fused: per-dst prefix across GB block-hists (leaves block offsets in hist,
// emits cnt) + block-level exclusive scan of counts -> rowStart, bsum.
__global__ void k_scan1(int* __restrict__ hist, int* __restrict__ cnt,
                        int* __restrict__ rowStart, int* __restrict__ bsum) {
    __shared__ int sh[256];
    int tid = threadIdx.x;
    int i = blockIdx.x*256 + tid;
    int run = 0;
    if (i < NNODES) {
        int g = i / NN, dl = i - g*NN;
        int* hbase = hist + (size_t)g*GB*NN + dl;
        #pragma unroll
        for (int b = 0; b < GB; ++b) {
            int v = hbase[(size_t)b*NN];
            hbase[(size_t)b*NN] = run;      // exclusive within-dst offset
            run += v;
        }
        cnt[i] = run;
    }
    sh[tid] = run;
    __syncthreads();
    for (int off = 1; off < 256; off <<= 1) {
        int t = (tid >= off) ? sh[tid - off] : 0;
        __syncthreads();
        sh[tid] += t;
        __syncthreads();
    }
    if (i < NNODES) rowStart[i] = sh[tid] - run;        // exclusive
    if (tid == 255) bsum[blockIdx.x] = sh[255];
}

__global__ void k_scan2(int* bsum) {
    __shared__ int sh[512];
    int tid = threadIdx.x;
    int v = (tid < NBLK) ? bsum[tid] : 0;
    sh[tid] = v;
    __syncthreads();
    for (int off = 1; off < 512; off <<= 1) {
        int t = (tid >= off) ? sh[tid - off] : 0;
        __syncthreads();
        sh[tid] += t;
        __syncthreads();
    }
    if (tid < NBLK) bsum[tid] = sh[tid] - v;            // exclusive
}

// add block offsets; compute dinv; prescale 5-dim features into SoA xs5
__global__ void k_scan3(int* __restrict__ rowStart, const int* __restrict__ bsum,
                        const int* __restrict__ cnt, float* __restrict__ dinv,
                        const float* __restrict__ x, float* __restrict__ xs5) {
    int i = blockIdx.x*256 + threadIdx.x;
    if (i < NNODES) {
        rowStart[i] = rowStart[i] + bsum[blockIdx.x];
        float dv = rsqrtf(1.0f + (float)cnt[i]);        // +1 = self loop
        dinv[i] = dv;
        #pragma unroll
        for (int f = 0; f < FIN; ++f)
            xs5[f*NNODES + i] = x[(size_t)i*FIN + f] * dv;
    }
    if (i == 0) rowStart[NNODES] = NEDGE;
}

// p = rowStart[dst] + blockOffset[b][dst] + rank_local[e]; plain stores only.
__global__ __launch_bounds__(256) void k_fillL(const int* __restrict__ edges,
                                               const int* __restrict__ rowStart,
                                               const int* __restrict__ hist,
                                               const int* __restrict__ rankL,
                                               int* __restrict__ csrSrc) {
    int g = blockIdx.x & 7;
    int b = blockIdx.x >> 3;
    const int* base = edges + (size_t)g*2*NE;
    const int4* s4p = (const int4*)(base + b*EPB);
    const int4* d4p = (const int4*)(base + NE + b*EPB);
    const int4* r4p = (const int4*)(rankL + (size_t)g*NE + b*EPB);
    const int* rs = rowStart + g*NN;
    const int* ho = hist + (size_t)(g*GB + b)*NN;
    int gofs = g*NN;
    for (int i = threadIdx.x; i < EPB/4; i += 256) {
        int4 s4 = s4p[i];
        int4 d4 = d4p[i];
        int4 r4 = r4p[i];
        csrSrc[rs[d4.x] + ho[d4.x] + r4.x] = s4.x + gofs;
        csrSrc[rs[d4.y] + ho[d4.y] + r4.y] = s4.y + gofs;
        csrSrc[rs[d4.z] + ho[d4.z] + r4.z] = s4.z + gofs;
        csrSrc[rs[d4.w] + ho[d4.w] + r4.w] = s4.w + gofs;
    }
}

// layer-1 aggregation on the 5 raw features (agg commutes with dense transform).
__global__ __launch_bounds__(256) void k_agg5(
        const int* __restrict__ rowStart, const int* __restrict__ csrSrc,
        const float* __restrict__ xs5, const float* __restrict__ dinv,
        float* __restrict__ ax) {
    int g = blockIdx.x;
    int graph = g & 7;
    int nl = (g >> 3)*256 + threadIdx.x;
    if (nl >= NN) return;
    int n = graph*NN + nl;
    float a0 = xs5[0*NNODES + n], a1 = xs5[1*NNODES + n], a2 = xs5[2*NNODES + n],
          a3 = xs5[3*NNODES + n], a4 = xs5[4*NNODES + n];
    int beg = rowStart[n], end = rowStart[n+1];
    for (int e = beg; e < end; ++e) {
        int s = csrSrc[e];
        a0 += xs5[0*NNODES + s];
        a1 += xs5[1*NNODES + s];
        a2 += xs5[2*NNODES + s];
        a3 += xs5[3*NNODES + s];
        a4 += xs5[4*NNODES + s];
    }
    float dv = dinv[n];
    ax[(size_t)n*FIN + 0] = a0*dv;
    ax[(size_t)n*FIN + 1] = a1*dv;
    ax[(size_t)n*FIN + 2] = a2*dv;
    ax[(size_t)n*FIN + 3] = a3*dv;
    ax[(size_t)n*FIN + 4] = a4*dv;
}

// Fused layer-1 dense + layer-2 dense, column-split for occupancy:
// block = 128 rows x 64 cols (jb = blockIdx&1 picks the column half), grid 1250.
#define KC 32
__global__ __launch_bounds__(256) void k_h12(
        const float* __restrict__ ax, const float* __restrict__ W1,
        const float* __restrict__ b1, const float* __restrict__ W2,
        const float* __restrict__ dinv, float* __restrict__ hs) {
    __shared__ float axs[FIN][128];
    __shared__ float w1s[FIN][128];
    __shared__ float b1s[128];
    __shared__ float xs[KC*128];
    __shared__ float wt[KC*64];
    int tid = threadIdx.x;
    int jb  = blockIdx.x & 1;               // column half: j in [jb*64, jb*64+64)
    int m0g = (blockIdx.x >> 1) * 128;
    if (tid < 128) {
        b1s[tid] = b1[tid];
        #pragma unroll
        for (int f = 0; f < FIN; ++f) w1s[f][tid] = W1[tid*FIN + f];
    } else {
        int r2 = tid - 128;
        #pragma unroll
        for (int f = 0; f < FIN; ++f) axs[f][r2] = ax[(size_t)(m0g + r2)*FIN + f];
    }
    int tx = tid & 15, ty = tid >> 4;
    int m0 = ty*8;                      // 16 groups x 8 rows = 128
    int j0 = tx*4;                      // 16 groups x 4 cols = 64
    int r  = tid >> 1;                  // H1 staging row 0..127
    int kq = (tid & 1) * 16;            // H1 staging k sub-chunk
    int rw  = tid >> 2;                 // W2 staging local col 0..63
    int kqw = (tid & 3) * 8;            // W2 staging k sub-chunk
    float a[8][4];
    #pragma unroll
    for (int i = 0; i < 8; ++i)
        #pragma unroll
        for (int j = 0; j < 4; ++j) a[i][j] = 0.f;
    __syncthreads();
    float axr[FIN];
    #pragma unroll
    for (int f = 0; f < FIN; ++f) axr[f] = axs[f][r];

    for (int kh = 0; kh < 128; kh += KC) {
        float4 wv0 = *(const float4*)&W2[(size_t)(jb*64 + rw)*128 + kh + kqw];
        float4 wv1 = *(const float4*)&W2[(size_t)(jb*64 + rw)*128 + kh + kqw + 4];
        float hv[16];
        #pragma unroll
        for (int kk = 0; kk < 16; ++kk) {
            int k1 = kh + kq + kk;
            float sv = b1s[k1];
            #pragma unroll
            for (int f = 0; f < FIN; ++f) sv += axr[f]*w1s[f][k1];
            hv[kk] = fmaxf(sv, 0.0f);
        }
        __syncthreads();               // protect prev iter's reads
        #pragma unroll
        for (int kk = 0; kk < 16; ++kk) xs[(kq+kk)*128 + r] = hv[kk];
        wt[(kqw+0)*64 + rw] = wv0.x;
        wt[(kqw+1)*64 + rw] = wv0.y;
        wt[(kqw+2)*64 + rw] = wv0.z;
        wt[(kqw+3)*64 + rw] = wv0.w;
        wt[(kqw+4)*64 + rw] = wv1.x;
        wt[(kqw+5)*64 + rw] = wv1.y;
        wt[(kqw+6)*64 + rw] = wv1.z;
        wt[(kqw+7)*64 + rw] = wv1.w;
        __syncthreads();
        for (int k = 0; k < KC; ++k) {
            float4 xa = *(const float4*)&xs[k*128 + m0];
            float4 xb = *(const float4*)&xs[k*128 + m0 + 4];
            float4 wa = *(const float4*)&wt[k*64 + j0];
            float xr[8] = {xa.x,xa.y,xa.z,xa.w,xb.x,xb.y,xb.z,xb.w};
            #pragma unroll
            for (int i = 0; i < 8; ++i) {
                a[i][0] += xr[i]*wa.x;
                a[i][1] += xr[i]*wa.y;
                a[i][2] += xr[i]*wa.z;
                a[i][3] += xr[i]*wa.w;
            }
        }
    }
    #pragma unroll
    for (int i = 0; i < 8; ++i) {
        int n = m0g + m0 + i;
        float dv = dinv[n];
        float4 v0 = make_float4(a[i][0]*dv, a[i][1]*dv, a[i][2]*dv, a[i][3]*dv);
        *(float4*)&hs[(size_t)n*HID + jb*64 + j0] = v0;
    }
}

// layer-2 aggregation ONLY at the 40 head positions (5 per batch x 8):
// out2[n] = relu(dinv[n]*(hs[n] + sum_{src in in(n)} hs[src]) + b2).
// One block per (batch,position), feature-per-lane, serial edge loop (~16 edges).
__global__ __launch_bounds__(128) void k_aggP(
        const int* __restrict__ rowStart, const int* __restrict__ csrSrc,
        const float* __restrict__ hs, const float* __restrict__ dinv,
        const float* __restrict__ bias,
        const int* __restrict__ avail, const int* __restrict__ pos,
        float* __restrict__ cx40) {
    int b = blockIdx.x / 5, pi = blockIdx.x - b*5;
    int n = (pi < 4 ? avail[b*4 + pi] : (int)pos[b]) + b*NN;
    int f = threadIdx.x;                // 0..127
    float acc = hs[(size_t)n*HID + f];  // self loop
    int beg = rowStart[n], end = rowStart[n+1];
    for (int e = beg; e < end; ++e) {
        int s = csrSrc[e];
        acc += hs[(size_t)s*HID + f];
    }
    cx40[(size_t)blockIdx.x*HID + f] = fmaxf(acc*dinv[n] + bias[f], 0.0f);
}

// MLP1: block per (batch, 16-output group); 16 lanes per output, shuffle-reduce.
// Reads the 40-position aggregated features (cx40) -- layout [b][pi][f] == b*640+i.
__global__ __launch_bounds__(256) void k_mlp1(
        const float* __restrict__ cx40, const float* __restrict__ actions,
        const float* __restrict__ steps,
        const float* __restrict__ Wp1, const float* __restrict__ bp1,
        float* __restrict__ hm) {
    int b  = blockIdx.x >> 4;
    int jg = blockIdx.x & 15;
    int t  = threadIdx.x;
    __shared__ float c[PROJ_IN];
    for (int i = t; i < 5*HID; i += 256)
        c[i] = cx40[(size_t)b*5*HID + i];
    if (t < ALAST) c[5*HID + t] = actions[b*ALAST + t];
    if (t == ALAST) c[5*HID + ALAST] = steps[b];
    __syncthreads();
    int o = t >> 4, sub = t & 15;
    int j = jg*16 + o;
    const float* wr = Wp1 + (size_t)j*PROJ_IN;
    float s = 0.f;
    for (int k = sub; k < PROJ_IN; k += 16) s += c[k]*wr[k];
    #pragma unroll
    for (int d = 8; d; d >>= 1) s += __shfl_down(s, d, 16);
    if (sub == 0) hm[b*EMB + j] = fmaxf(s + bp1[j], 0.f);
}

// MLP2: block per (batch, 16-output group); 16 lanes per output, shuffle-reduce.
__global__ __launch_bounds__(256) void k_mlp2(
        const float* __restrict__ hm, const float* __restrict__ Wp2,
        const float* __restrict__ bp2, float* __restrict__ out) {
    int b  = blockIdx.x >> 4;
    int jg = blockIdx.x & 15;
    int t  = threadIdx.x;
    __shared__ float c[EMB];
    if (t < EMB) c[t] = hm[b*EMB + t];
    __syncthreads();
    int o = t >> 4, sub = t & 15;
    int j = jg*16 + o;
    const float* wr = Wp2 + (size_t)j*EMB;
    float s = 0.f;
    for (int k = sub; k < EMB; k += 16) s += c[k]*wr[k];
    #pragma unroll
    for (int d = 8; d; d >>= 1) s += __shfl_down(s, d, 16);
    if (sub == 0) out[b*EMB + j] = s + bp2[j];
}

extern "C" void kernel_launch(void* const* d_in, const int* in_sizes, int n_in,
                              void* d_out, int out_size, void* d_ws, size_t ws_size,
                              hipStream_t stream) {
    const float* graph_x = (const float*)d_in[0];
    const int*   edges   = (const int*)d_in[1];
    const int*   pos     = (const int*)d_in[2];
    const int*   avail   = (const int*)d_in[3];
    const float* actions = (const float*)d_in[4];
    const float* steps   = (const float*)d_in[5];
    const float* W1  = (const float*)d_in[6];
    const float* b1  = (const float*)d_in[7];
    const float* W2  = (const float*)d_in[8];
    const float* b2  = (const float*)d_in[9];
    const float* Wp1 = (const float*)d_in[10];
    const float* bp1 = (const float*)d_in[11];
    const float* Wp2 = (const float*)d_in[12];
    const float* bp2 = (const float*)d_in[13];
    float* out = (float*)d_out;

    char* ws = (char*)d_ws;
    size_t off = 0;
    #define ALLOC(ptrname, type, nelem) \
        type* ptrname = (type*)(ws + off); off = (off + (size_t)(nelem)*sizeof(type) + 255) & ~(size_t)255;
    ALLOC(cnt,      int,   NNODES)
    ALLOC(rowStart, int,   NNODES+1)
    ALLOC(bsum,     int,   512)
    ALLOC(hist,     int,   (size_t)NB*GB*NN)     // per-block histograms / offsets
    ALLOC(rankL,    int,   NEDGE)
    ALLOC(csrSrc,   int,   NEDGE)
    ALLOC(dinv,     float, NNODES)
    ALLOC(xs5,      float, (size_t)NNODES*FIN)   // SoA prescaled input
    ALLOC(ax,       float, (size_t)NNODES*FIN)   // aggregated 5-dim
    ALLOC(bufA,     float, (size_t)NNODES*HID)   // hs (layer-2 dense, pre-agg)
    ALLOC(cx40,     float, (size_t)NB*5*HID)     // aggregated features at 40 positions
    ALLOC(hm,       float, (size_t)NB*EMB)
    #undef ALLOC

    // CSR build: LDS histograms, no global atomics
    k_histL<<<NB*GB, 256, 0, stream>>>(edges, hist, rankL);
    k_scan1<<<NBLK, 256, 0, stream>>>(hist, cnt, rowStart, bsum);
    k_scan2<<<1, 512, 0, stream>>>(bsum);
    k_scan3<<<NBLK, 256, 0, stream>>>(rowStart, bsum, cnt, dinv, graph_x, xs5);
    k_fillL<<<NB*GB, 256, 0, stream>>>(edges, rowStart, hist, rankL, csrSrc);

    // layer 1 aggregation on 5-dim raw features
    k_agg5<<<8*((NN+255)/256), 256, 0, stream>>>(rowStart, csrSrc, xs5, dinv, ax);

    // fused layer-1 dense + layer-2 dense (column-split, grid 1250)
    k_h12<<<(NNODES/128)*2, 256, 0, stream>>>(ax, W1, b1, W2, dinv, bufA);

    // layer-2 aggregation at the 40 head positions only
    k_aggP<<<NB*5, 128, 0, stream>>>(rowStart, csrSrc, bufA, dinv, b2, avail, pos, cx40);

    // head
    k_mlp1<<<NB*16, 256, 0, stream>>>(cx40, actions, steps, Wp1, bp1, hm);
    k_mlp2<<<NB*16, 256, 0, stream>>>(hm, Wp2, bp2, out);
}